// Round 1
// baseline (190.647 us; speedup 1.0000x reference)
//
#include <hip/hip_runtime.h>
#include <stdint.h>

// Problem constants (B,C,D,H,W) = (2,1,128,256,256)
#define BB 2
#define DD 128
#define HH 256
#define WW 256
static constexpr int64_t N = (int64_t)BB * DD * HH * WW;   // 16,777,216
static constexpr int WPR   = WW / 64;                      // 4 words per row
static constexpr int ROWS  = BB * DD * HH;                 // 65,536 rows
static constexpr int NWORDS = ROWS * WPR;                  // 262,144 words (2 MB)

// ---------------------------------------------------------------------------
// K1: predicate + X-dilation (radius 3), bit-packed.
// Block = 256 threads, each thread loads a float4 -> block covers 1024 voxels
// = 4 full W-rows = 16 uint64 words. X dilation done per-row with carries.
// ---------------------------------------------------------------------------
__global__ __launch_bounds__(256) void mask_xdil(const float* __restrict__ tgt,
                                                 uint64_t* __restrict__ mask) {
    const int tid = threadIdx.x;
    const int64_t base = (int64_t)blockIdx.x * 1024;
    float4 t = ((const float4*)(tgt + base))[tid];

    unsigned nib = 0;
    nib |= (t.x > 0.0f && t.x < 1.0f) ? 1u : 0u;
    nib |= (t.y > 0.0f && t.y < 1.0f) ? 2u : 0u;
    nib |= (t.z > 0.0f && t.z < 1.0f) ? 4u : 0u;
    nib |= (t.w > 0.0f && t.w < 1.0f) ? 8u : 0u;

    __shared__ unsigned char nibs[256];
    __shared__ uint64_t words[16];
    nibs[tid] = (unsigned char)nib;
    __syncthreads();

    if (tid < 16) {
        uint64_t w = 0;
        #pragma unroll
        for (int i = 0; i < 16; i++)
            w |= (uint64_t)(nibs[tid * 16 + i] & 0xF) << (4 * i);
        words[tid] = w;
    }
    __syncthreads();

    if (tid < 16) {
        const int wx = tid & 3;                 // word-in-row; rows of 4 words
        const uint64_t C = words[tid];
        const uint64_t L = (wx > 0) ? words[tid - 1] : 0ull;
        const uint64_t R = (wx < 3) ? words[tid + 1] : 0ull;
        uint64_t d = C;
        #pragma unroll
        for (int s = 1; s <= 3; s++) {
            d |= (C << s) | (C >> s);
            d |= (L >> (64 - s));
            d |= (R << (64 - s));
        }
        mask[(int64_t)blockIdx.x * 16 + tid] = d;
    }
}

// ---------------------------------------------------------------------------
// K2: Y and Z dilation (radius 3 each) on the packed mask: OR of up to 49
// neighbor words. 2 MB footprint -> L2-resident.
// ---------------------------------------------------------------------------
__global__ __launch_bounds__(256) void yz_dil(const uint64_t* __restrict__ in,
                                              uint64_t* __restrict__ out) {
    const int n = blockIdx.x * blockDim.x + threadIdx.x;
    if (n >= NWORDS) return;
    const int wx = n & 3;
    const int y  = (n >> 2) & (HH - 1);
    const int z  = (n >> 10) & (DD - 1);
    const int b  = n >> 17;

    const int z0 = max(z - 3, 0), z1 = min(z + 3, DD - 1);
    const int y0 = max(y - 3, 0), y1 = min(y + 3, HH - 1);

    uint64_t acc = 0;
    for (int zz = z0; zz <= z1; zz++) {
        const uint64_t* p = in + (((int64_t)(b * DD + zz) * HH) + y0) * WPR + wx;
        for (int yy = y0; yy <= y1; yy++) {
            acc |= *p;
            p += WPR;
        }
    }
    out[n] = acc;
}

// ---------------------------------------------------------------------------
// K3: weighted L1 reduction. float4 loads of input/target, mask nibble per
// float4, wave shuffle reduce -> LDS -> one double atomicAdd per block.
// ---------------------------------------------------------------------------
__global__ __launch_bounds__(256) void reduce_loss(const float* __restrict__ inp,
                                                   const float* __restrict__ tgt,
                                                   const uint64_t* __restrict__ mask,
                                                   double* __restrict__ acc) {
    const int64_t nvec = N / 4;
    const int64_t stride = (int64_t)gridDim.x * blockDim.x;
    float local = 0.0f;
    for (int64_t i = (int64_t)blockIdx.x * blockDim.x + threadIdx.x; i < nvec; i += stride) {
        float4 a = ((const float4*)inp)[i];
        float4 t = ((const float4*)tgt)[i];
        uint64_t w = mask[i >> 4];
        unsigned nib = (unsigned)(w >> ((i & 15) * 4)) & 0xFu;
        float s;
        s  = fabsf(t.x - a.x) * ((nib & 1u) ? 11.0f : 1.0f);
        s += fabsf(t.y - a.y) * ((nib & 2u) ? 11.0f : 1.0f);
        s += fabsf(t.z - a.z) * ((nib & 4u) ? 11.0f : 1.0f);
        s += fabsf(t.w - a.w) * ((nib & 8u) ? 11.0f : 1.0f);
        local += s;
    }
    // wave (64-lane) reduction
    #pragma unroll
    for (int off = 32; off > 0; off >>= 1)
        local += __shfl_down(local, off, 64);
    __shared__ float wsum[4];
    const int lane = threadIdx.x & 63;
    const int wv   = threadIdx.x >> 6;
    if (lane == 0) wsum[wv] = local;
    __syncthreads();
    if (threadIdx.x == 0) {
        float b = wsum[0] + wsum[1] + wsum[2] + wsum[3];
        atomicAdd(acc, (double)b);
    }
}

__global__ void finalize(const double* __restrict__ acc, float* __restrict__ out) {
    out[0] = (float)(acc[0] * (1.0 / (double)N));
}

extern "C" void kernel_launch(void* const* d_in, const int* in_sizes, int n_in,
                              void* d_out, int out_size, void* d_ws, size_t ws_size,
                              hipStream_t stream) {
    const float* inp = (const float*)d_in[0];   // "input"
    const float* tgt = (const float*)d_in[1];   // "target"
    float* out = (float*)d_out;

    double*   acc   = (double*)d_ws;                          // 8 B accumulator
    uint64_t* mask0 = (uint64_t*)((char*)d_ws + 256);         // 2 MB
    uint64_t* mask1 = mask0 + NWORDS;                         // 2 MB

    hipMemsetAsync(d_ws, 0, 16, stream);  // zero the accumulator (ws is poisoned)

    mask_xdil<<<(int)(N / 1024), 256, 0, stream>>>(tgt, mask0);
    yz_dil<<<(NWORDS + 255) / 256, 256, 0, stream>>>(mask0, mask1);
    reduce_loss<<<4096, 256, 0, stream>>>(inp, tgt, mask1, acc);
    finalize<<<1, 1, 0, stream>>>(acc, out);
}

// Round 2
// 151.561 us; speedup vs baseline: 1.2579x; 1.2579x over previous
//
#include <hip/hip_runtime.h>
#include <stdint.h>

// Problem constants (B,C,D,H,W) = (2,1,128,256,256)
#define BB 2
#define DD 128
#define HH 256
#define WW 256
static constexpr int64_t N = (int64_t)BB * DD * HH * WW;   // 16,777,216
static constexpr int WPR    = WW / 64;                     // 4 words per row
static constexpr int NWORDS = BB * DD * HH * WPR;          // 262,144 words (2 MB)
static constexpr int ZSTR   = HH * WPR;                    // 1024 words per z-plane
static constexpr int RBLOCKS = 4096;                       // reduce grid

// ---------------------------------------------------------------------------
// K1: predicate + X-dilation (radius 3), bit-packed. Block covers 1024 voxels
// = 4 full W-rows = 16 uint64 words. X dilation via 64-bit shifts w/ carries.
// ---------------------------------------------------------------------------
__global__ __launch_bounds__(256) void mask_xdil(const float* __restrict__ tgt,
                                                 uint64_t* __restrict__ mask) {
    const int tid = threadIdx.x;
    const int64_t base = (int64_t)blockIdx.x * 1024;
    float4 t = ((const float4*)(tgt + base))[tid];

    unsigned nib = 0;
    nib |= (t.x > 0.0f && t.x < 1.0f) ? 1u : 0u;
    nib |= (t.y > 0.0f && t.y < 1.0f) ? 2u : 0u;
    nib |= (t.z > 0.0f && t.z < 1.0f) ? 4u : 0u;
    nib |= (t.w > 0.0f && t.w < 1.0f) ? 8u : 0u;

    __shared__ unsigned char nibs[256];
    __shared__ uint64_t words[16];
    nibs[tid] = (unsigned char)nib;
    __syncthreads();

    if (tid < 16) {
        uint64_t w = 0;
        #pragma unroll
        for (int i = 0; i < 16; i++)
            w |= (uint64_t)(nibs[tid * 16 + i] & 0xF) << (4 * i);
        words[tid] = w;
    }
    __syncthreads();

    if (tid < 16) {
        const int wx = tid & 3;                 // word-in-row; rows of 4 words
        const uint64_t C = words[tid];
        const uint64_t L = (wx > 0) ? words[tid - 1] : 0ull;
        const uint64_t R = (wx < 3) ? words[tid + 1] : 0ull;
        uint64_t d = C;
        #pragma unroll
        for (int s = 1; s <= 3; s++) {
            d |= (C << s) | (C >> s);
            d |= (L >> (64 - s));
            d |= (R << (64 - s));
        }
        mask[(int64_t)blockIdx.x * 16 + tid] = d;
    }
}

// ---------------------------------------------------------------------------
// K2a: Y dilation (radius 3). 7 fully-unrolled predicated loads per word.
// ---------------------------------------------------------------------------
__global__ __launch_bounds__(256) void y_dil(const uint64_t* __restrict__ in,
                                             uint64_t* __restrict__ out) {
    const int n = blockIdx.x * 256 + threadIdx.x;
    const int y = (n >> 2) & (HH - 1);
    uint64_t acc = 0;
    #pragma unroll
    for (int dy = -3; dy <= 3; dy++) {
        const int yy = y + dy;
        acc |= (yy >= 0 && yy < HH) ? in[n + dy * WPR] : 0ull;
    }
    out[n] = acc;
}

// ---------------------------------------------------------------------------
// K2b: Z dilation (radius 3). 7 fully-unrolled predicated loads per word.
// ---------------------------------------------------------------------------
__global__ __launch_bounds__(256) void z_dil(const uint64_t* __restrict__ in,
                                             uint64_t* __restrict__ out) {
    const int n = blockIdx.x * 256 + threadIdx.x;
    const int z = (n >> 10) & (DD - 1);
    uint64_t acc = 0;
    #pragma unroll
    for (int dz = -3; dz <= 3; dz++) {
        const int zz = z + dz;
        acc |= (zz >= 0 && zz < DD) ? in[n + dz * ZSTR] : 0ull;
    }
    out[n] = acc;
}

// ---------------------------------------------------------------------------
// K3: weighted L1 partial reduction. float4 loads, mask nibble per float4,
// wave shuffle -> LDS -> ONE non-atomic double store per block.
// ---------------------------------------------------------------------------
__global__ __launch_bounds__(256) void reduce_loss(const float* __restrict__ inp,
                                                   const float* __restrict__ tgt,
                                                   const uint64_t* __restrict__ mask,
                                                   double* __restrict__ partials) {
    const int64_t nvec = N / 4;
    const int64_t stride = (int64_t)RBLOCKS * 256;
    float local = 0.0f;
    for (int64_t i = (int64_t)blockIdx.x * 256 + threadIdx.x; i < nvec; i += stride) {
        float4 a = ((const float4*)inp)[i];
        float4 t = ((const float4*)tgt)[i];
        uint64_t w = mask[i >> 4];
        unsigned nib = (unsigned)(w >> ((i & 15) * 4)) & 0xFu;
        float s;
        s  = fabsf(t.x - a.x) * ((nib & 1u) ? 11.0f : 1.0f);
        s += fabsf(t.y - a.y) * ((nib & 2u) ? 11.0f : 1.0f);
        s += fabsf(t.z - a.z) * ((nib & 4u) ? 11.0f : 1.0f);
        s += fabsf(t.w - a.w) * ((nib & 8u) ? 11.0f : 1.0f);
        local += s;
    }
    #pragma unroll
    for (int off = 32; off > 0; off >>= 1)
        local += __shfl_down(local, off, 64);
    __shared__ float wsum[4];
    const int lane = threadIdx.x & 63;
    const int wv   = threadIdx.x >> 6;
    if (lane == 0) wsum[wv] = local;
    __syncthreads();
    if (threadIdx.x == 0)
        partials[blockIdx.x] = (double)(wsum[0] + wsum[1] + wsum[2] + wsum[3]);
}

// ---------------------------------------------------------------------------
// K4: sum 4096 double partials, divide by N.
// ---------------------------------------------------------------------------
__global__ __launch_bounds__(1024) void finalize(const double* __restrict__ partials,
                                                 float* __restrict__ out) {
    double local = 0.0;
    for (int i = threadIdx.x; i < RBLOCKS; i += 1024) local += partials[i];
    #pragma unroll
    for (int off = 32; off > 0; off >>= 1)
        local += __shfl_down(local, off, 64);
    __shared__ double ws[16];
    const int lane = threadIdx.x & 63;
    const int wv   = threadIdx.x >> 6;
    if (lane == 0) ws[wv] = local;
    __syncthreads();
    if (threadIdx.x == 0) {
        double s = 0.0;
        #pragma unroll
        for (int k = 0; k < 16; k++) s += ws[k];
        out[0] = (float)(s / (double)N);
    }
}

extern "C" void kernel_launch(void* const* d_in, const int* in_sizes, int n_in,
                              void* d_out, int out_size, void* d_ws, size_t ws_size,
                              hipStream_t stream) {
    const float* inp = (const float*)d_in[0];   // "input"
    const float* tgt = (const float*)d_in[1];   // "target"
    float* out = (float*)d_out;

    double*   partials = (double*)d_ws;                        // 32 KB (fully written)
    uint64_t* mask0 = (uint64_t*)((char*)d_ws + 64 * 1024);    // 2 MB
    uint64_t* mask1 = mask0 + NWORDS;                          // 2 MB

    mask_xdil<<<(int)(N / 1024), 256, 0, stream>>>(tgt, mask0);
    y_dil<<<NWORDS / 256, 256, 0, stream>>>(mask0, mask1);
    z_dil<<<NWORDS / 256, 256, 0, stream>>>(mask1, mask0);
    reduce_loss<<<RBLOCKS, 256, 0, stream>>>(inp, tgt, mask0, partials);
    finalize<<<1, 1024, 0, stream>>>(partials, out);
}